// Round 10
// baseline (416.458 us; speedup 1.0000x reference)
//
#include <hip/hip_runtime.h>
#include <hip/hip_bf16.h>

#define BB 4
#define H_ 128
#define W_ 128
#define HWP 16384
#define CIN1 64
#define CMID 128
#define KOFF 18

typedef short short8 __attribute__((ext_vector_type(8)));
typedef float floatx4 __attribute__((ext_vector_type(4)));

// ---- workspace layout (float offsets) ----
#define WS_AB   16
#define WS_CVT  288
#define CVT_TOTAL 4447396
#define WS_WF1  4447744
#define WS_WF2  4484608
#define WS_XT   4558336
#define WS_OFF  6655488
#define WS_Y1   7835136
#define WS_Y1T  16223744
#define WS_PART 21600000
#define WS_Y2   WS_Y1

// cvt-relative input offsets
#define R_X     0
#define R_WOFF1 4194304
#define R_BOFF1 4204672
#define R_W1    4204690
#define R_B1    4278418
#define R_G1    4278546
#define R_BE1   4278674
#define R_WOFF2 4278802
#define R_BOFF2 4299538
#define R_W2    4299556
#define R_B2    4447012
#define R_G2    4447140
#define R_BE2   4447268

struct SrcPtrs { const void* p[13]; };

__device__ inline short f2bf(float f) {
    __hip_bfloat16 h = __float2bfloat16(f);
    return *reinterpret_cast<short*>(&h);
}
__device__ inline float bf2f(unsigned short u) {
    return __uint_as_float(((unsigned int)u) << 16);
}
__device__ inline float bfu_lo(unsigned int u) { return __uint_as_float(u << 16); }
__device__ inline float bfu_hi(unsigned int u) { return __uint_as_float(u & 0xFFFF0000u); }
__device__ inline float rl_f(float v, int i) {
    return __int_as_float(__builtin_amdgcn_readlane(__float_as_int(v), i));
}

__global__ void probe_dtype_k(const unsigned int* __restrict__ g1, int* __restrict__ flag) {
    if (threadIdx.x == 0 && blockIdx.x == 0) {
        flag[0] = ((g1[0] & 0xFFFFu) != 0u) ? 1 : 0;
    }
}

__global__ __launch_bounds__(256) void convert_inputs_k(SrcPtrs sp, float* __restrict__ dst,
                                                        const int* __restrict__ flag, int total) {
    int i = blockIdx.x * 256 + threadIdx.x;
    if (i >= total) return;
    constexpr int prefix[13] = {0, R_WOFF1, R_BOFF1, R_W1, R_B1, R_G1, R_BE1,
                                R_WOFF2, R_BOFF2, R_W2, R_B2, R_G2, R_BE2};
    const void* src = sp.p[0];
    int base = 0;
#pragma unroll
    for (int q = 1; q < 13; ++q) {
        if (i >= prefix[q]) { src = sp.p[q]; base = prefix[q]; }
    }
    int local = i - base;
    float v;
    if (flag[0] != 0) {
        v = bf2f(((const unsigned short*)src)[local]);
    } else {
        v = ((const float*)src)[local];
    }
    dst[i] = v;
}

// Pack conv weights into MFMA A-fragment order; frag-k = kk*CIN + ci
template <int CIN>
__global__ __launch_bounds__(256) void wf_build_k(const float* __restrict__ w, short* __restrict__ wf) {
    constexpr int KSTEPS = CIN * 9 / 32;
    int idx = blockIdx.x * 256 + threadIdx.x;
    int j    = idx & 7;
    int lane = (idx >> 3) & 63;
    int rem  = idx >> 9;
    int ks   = rem % KSTEPS;
    int ct   = rem / KSTEPS;
    int co = ct * 16 + (lane & 15);
    int k  = ks * 32 + (lane >> 4) * 8 + j;
    int ci = k & (CIN - 1);
    int kk = k / CIN;
    wf[idx] = f2bf(w[(co * CIN + ci) * 9 + kk]);
}

// X (fp32 NCHW, C=64) -> XT (bf16 NHWC)
__global__ __launch_bounds__(256) void xt_build_k(const float* __restrict__ x, unsigned short* __restrict__ xt) {
    __shared__ __align__(4) short s_t[64 * 66];
    int bi  = blockIdx.x;           // 4 * 256
    int hw0 = (bi & 255) * 64;
    int b   = bi >> 8;
    int t   = threadIdx.x;
    int hwp = t & 63;
#pragma unroll
    for (int it = 0; it < 16; ++it) {
        int c = it * 4 + (t >> 6);
        float v = x[((long)(b * 64 + c) << 14) + hw0 + hwp];
        s_t[hwp * 66 + c] = f2bf(v);
    }
    __syncthreads();
#pragma unroll
    for (int it = 0; it < 8; ++it) {
        int i  = it * 256 + t;
        int c2 = (i & 31) * 2;
        int hw2 = i >> 5;
        int sv = *(const int*)&s_t[hw2 * 66 + c2];
        *(int*)&xt[((long)((b << 14) + hw0 + hw2)) * 64 + c2] = sv;
    }
}

// Offset conv3x3, pad=1, CO=18, ci-QUARTER split, atomicAdd accumulation.
template <int CIN>
__global__ __launch_bounds__(256) void conv3x3_atomic_k(const float* __restrict__ x,
                                                        const float* __restrict__ w,
                                                        const float* __restrict__ bias,
                                                        float* __restrict__ outp) {
    constexpr int CIQ = CIN / 4;
    int bi = blockIdx.x;
    int h  = bi & 127;
    int b  = (bi >> 7) & 3;
    int q  = bi >> 9;
    int t  = threadIdx.x;
    int wq = t & 127;
    int cg = __builtin_amdgcn_readfirstlane(t >> 7);
    int co0 = cg * 9;
    int ci0 = q * CIQ;

    float acc[9];
#pragma unroll
    for (int j = 0; j < 9; ++j) acc[j] = (q == 0) ? bias[co0 + j] : 0.f;

    const float* xb = x + ((long)(b * CIN + ci0) << 14);
    bool bm = h > 0, bp = h < H_ - 1, bl = wq > 0, br = wq < W_ - 1;
    int rm = (bm ? h - 1 : 0) << 7;
    int rc = h << 7;
    int rp = (bp ? h + 1 : H_ - 1) << 7;

#pragma unroll 2
    for (int ci = 0; ci < CIQ; ++ci) {
        const float* plane = xb + ((long)ci << 14);
        float v0 = plane[rm + wq - 1], v1 = plane[rm + wq], v2 = plane[rm + wq + 1];
        float v3 = plane[rc + wq - 1], v4 = plane[rc + wq], v5 = plane[rc + wq + 1];
        float v6 = plane[rp + wq - 1], v7 = plane[rp + wq], v8 = plane[rp + wq + 1];
        v0 = (bm && bl) ? v0 : 0.f;
        v1 = bm ? v1 : 0.f;
        v2 = (bm && br) ? v2 : 0.f;
        v3 = bl ? v3 : 0.f;
        v5 = br ? v5 : 0.f;
        v6 = (bp && bl) ? v6 : 0.f;
        v7 = bp ? v7 : 0.f;
        v8 = (bp && br) ? v8 : 0.f;
#pragma unroll
        for (int j = 0; j < 9; ++j) {
            const float* wk = w + ((long)(co0 + j) * CIN + ci0 + ci) * 9;
            acc[j] += v0 * wk[0] + v1 * wk[1] + v2 * wk[2]
                    + v3 * wk[3] + v4 * wk[4] + v5 * wk[5]
                    + v6 * wk[6] + v7 * wk[7] + v8 * wk[8];
        }
    }

    long ob = ((long)(b * KOFF + co0) << 14) + (h << 7) + wq;
#pragma unroll
    for (int j = 0; j < 9; ++j) atomicAdd(&outp[ob + ((long)j << 14)], acc[j]);
}

// ---- per-wave bilinear table, 3 register sets ----
// set s: lane holds entry for (p = lane&15, kk = s*4 + (lane>>4)); kk>=9 zeroed.
// readlane index for (p, kk=c): set c>>2, lane ((c&3)<<4)|p.
__device__ inline void build_table3(const float* __restrict__ off, int b, int h, int wpx0, int lane,
                                    int (&tpk)[3], float (&t0)[3], float (&t1)[3],
                                    float (&t2)[3], float (&t3)[3]) {
#pragma unroll
    for (int s = 0; s < 3; ++s) {
        tpk[s] = 0; t0[s] = t1[s] = t2[s] = t3[s] = 0.f;
        int kk = s * 4 + (lane >> 4);
        int p  = lane & 15;
        if (kk < 9) {
            int wpix = wpx0 + p;
            long obase = ((long)(b * KOFF) << 14) + (h << 7) + wpix;
            float oy = off[obase + ((long)(2 * kk) << 14)];
            float ox = off[obase + ((long)(2 * kk + 1) << 14)];
            float py = (float)(h - 1 + (kk / 3)) + oy;
            float px = (float)(wpix - 1 + (kk % 3)) + ox;
            float fy = floorf(py), fx = floorf(px);
            float wy = py - fy, wx = px - fx;
            int y0 = (int)fy, x0 = (int)fx;
            int y1 = y0 + 1, x1 = x0 + 1;
            bool vy0 = (y0 >= 0) && (y0 < H_);
            bool vy1 = (y1 >= 0) && (y1 < H_);
            bool vx0 = (x0 >= 0) && (x0 < W_);
            bool vx1 = (x1 >= 0) && (x1 < W_);
            float wy0 = 1.f - wy, wx0 = 1.f - wx;
            t0[s] = (vy0 && vx0) ? wy0 * wx0 : 0.f;
            t1[s] = (vy0 && vx1) ? wy0 * wx  : 0.f;
            t2[s] = (vy1 && vx0) ? wy  * wx0 : 0.f;
            t3[s] = (vy1 && vx1) ? wy  * wx  : 0.f;
            int iy0 = min(max(y0, 0), H_ - 1), iy1 = min(max(y1, 0), H_ - 1);
            int ix0 = min(max(x0, 0), W_ - 1), ix1 = min(max(x1, 0), W_ - 1);
            tpk[s] = (iy0 * W_ + ix0) | ((ix1 - ix0) << 14) | ((iy1 - iy0) << 15);
        }
    }
}

// Deform conv, CIN=128: block = 64 px (wave-private 16 px), all 128 co per wave.
// No __syncthreads — samples are wave-private LDS; wf shared via L1.
__global__ __launch_bounds__(256, 4) void deform_mfma128_k(const unsigned short* __restrict__ xt,
                                                           const float* __restrict__ off,
                                                           const short* __restrict__ wf,
                                                           const float* __restrict__ bias,
                                                           float* __restrict__ out) {
    constexpr int PADR = 136;     // shorts per px row (128 + 8 pad)
    __shared__ __align__(16) short s_samp[64 * PADR];

    int bi  = blockIdx.x;         // 2 wblocks * 128 h * 4 b
    int w0b = (bi & 1) * 64;
    int h   = (bi >> 1) & 127;
    int b   = bi >> 8;
    int t = threadIdx.x;
    int lane = t & 63, wv = t >> 6;
    int wpx0 = w0b + wv * 16;

    int tpk[3]; float t0[3], t1[3], t2[3], t3[3];
    build_table3(off, b, h, wpx0, lane, tpk, t0, t1, t2, t3);

    const unsigned short* xb = xt + (long)b * HWP * 128;
    short* sw = s_samp + wv * 16 * PADR;
    int p_ = lane & 15, quad = lane >> 4;

    floatx4 acc[8];
#pragma unroll
    for (int ct = 0; ct < 8; ++ct)
#pragma unroll
        for (int r = 0; r < 4; ++r) acc[ct][r] = bias[ct * 16 + quad * 4 + r];

#pragma unroll
    for (int c = 0; c < 9; ++c) {
        int s = c >> 2;
        // gather 16 px (this wave's), 4-px batches, lane = ci pair 2*lane
#pragma unroll
        for (int pb = 0; pb < 4; ++pb) {
            uint4 u[4]; float a0[4], a1[4], a2[4], a3[4];
#pragma unroll
            for (int j = 0; j < 4; ++j) {
                int li = ((c & 3) << 4) | (pb * 4 + j);
                int pk = __builtin_amdgcn_readlane(tpk[s], li);
                a0[j] = rl_f(t0[s], li); a1[j] = rl_f(t1[s], li);
                a2[j] = rl_f(t2[s], li); a3[j] = rl_f(t3[s], li);
                const unsigned short* b00 = xb + (pk & 0x3FFF) * 128;
                const unsigned short* b01 = b00 + ((pk >> 14) & 1) * 128;
                const unsigned short* b10 = b00 + ((pk >> 15) & 1) * (W_ * 128);
                const unsigned short* b11 = b01 + ((pk >> 15) & 1) * (W_ * 128);
                u[j].x = *(const unsigned int*)(b00 + 2 * lane);
                u[j].y = *(const unsigned int*)(b01 + 2 * lane);
                u[j].z = *(const unsigned int*)(b10 + 2 * lane);
                u[j].w = *(const unsigned int*)(b11 + 2 * lane);
            }
#pragma unroll
            for (int j = 0; j < 4; ++j) {
                float vlo = a0[j] * bfu_lo(u[j].x) + a1[j] * bfu_lo(u[j].y)
                          + a2[j] * bfu_lo(u[j].z) + a3[j] * bfu_lo(u[j].w);
                float vhi = a0[j] * bfu_hi(u[j].x) + a1[j] * bfu_hi(u[j].y)
                          + a2[j] * bfu_hi(u[j].z) + a3[j] * bfu_hi(u[j].w);
                __hip_bfloat162 h2 = __float22bfloat162_rn(make_float2(vlo, vhi));
                *(unsigned int*)&sw[(pb * 4 + j) * PADR + 2 * lane] = *reinterpret_cast<unsigned int*>(&h2);
            }
        }
        // MFMA: 4 ks steps of this kk chunk, 8 co-tiles each
#pragma unroll
        for (int ksl = 0; ksl < 4; ++ksl) {
            int ks = c * 4 + ksl;
            short8 bfrag = *(const short8*)&sw[p_ * PADR + ksl * 32 + quad * 8];
#pragma unroll
            for (int ct = 0; ct < 8; ++ct) {
                short8 a = *(const short8*)&wf[(((long)ct * 36 + ks) * 64 + lane) * 8];
                acc[ct] = __builtin_amdgcn_mfma_f32_16x16x32_bf16(a, bfrag, acc[ct], 0, 0, 0);
            }
        }
    }

    long ob = ((long)(b * 128) << 14) + (h << 7) + wpx0 + p_;
#pragma unroll
    for (int ct = 0; ct < 8; ++ct)
#pragma unroll
        for (int r = 0; r < 4; ++r)
            out[ob + ((long)(ct * 16 + quad * 4 + r) << 14)] = acc[ct][r];
}

// Deform conv, CIN=64: same tiling; lane = ci (ushort loads), 2 ks per chunk.
__global__ __launch_bounds__(256, 4) void deform_mfma64_k(const unsigned short* __restrict__ xt,
                                                          const float* __restrict__ off,
                                                          const short* __restrict__ wf,
                                                          const float* __restrict__ bias,
                                                          float* __restrict__ out) {
    constexpr int PADR = 72;      // 64 + 8 pad
    __shared__ __align__(16) short s_samp[64 * PADR];

    int bi  = blockIdx.x;
    int w0b = (bi & 1) * 64;
    int h   = (bi >> 1) & 127;
    int b   = bi >> 8;
    int t = threadIdx.x;
    int lane = t & 63, wv = t >> 6;
    int wpx0 = w0b + wv * 16;

    int tpk[3]; float t0[3], t1[3], t2[3], t3[3];
    build_table3(off, b, h, wpx0, lane, tpk, t0, t1, t2, t3);

    const unsigned short* xb = xt + (long)b * HWP * 64;
    short* sw = s_samp + wv * 16 * PADR;
    int p_ = lane & 15, quad = lane >> 4;

    floatx4 acc[8];
#pragma unroll
    for (int ct = 0; ct < 8; ++ct)
#pragma unroll
        for (int r = 0; r < 4; ++r) acc[ct][r] = bias[ct * 16 + quad * 4 + r];

#pragma unroll
    for (int c = 0; c < 9; ++c) {
        int s = c >> 2;
#pragma unroll
        for (int pb = 0; pb < 4; ++pb) {
            unsigned short q0[4], q1[4], q2[4], q3[4];
            float a0[4], a1[4], a2[4], a3[4];
#pragma unroll
            for (int j = 0; j < 4; ++j) {
                int li = ((c & 3) << 4) | (pb * 4 + j);
                int pk = __builtin_amdgcn_readlane(tpk[s], li);
                a0[j] = rl_f(t0[s], li); a1[j] = rl_f(t1[s], li);
                a2[j] = rl_f(t2[s], li); a3[j] = rl_f(t3[s], li);
                const unsigned short* b00 = xb + (pk & 0x3FFF) * 64;
                const unsigned short* b01 = b00 + ((pk >> 14) & 1) * 64;
                const unsigned short* b10 = b00 + ((pk >> 15) & 1) * (W_ * 64);
                const unsigned short* b11 = b01 + ((pk >> 15) & 1) * (W_ * 64);
                q0[j] = b00[lane]; q1[j] = b01[lane]; q2[j] = b10[lane]; q3[j] = b11[lane];
            }
#pragma unroll
            for (int j = 0; j < 4; ++j) {
                float v = a0[j] * bf2f(q0[j]) + a1[j] * bf2f(q1[j])
                        + a2[j] * bf2f(q2[j]) + a3[j] * bf2f(q3[j]);
                sw[(pb * 4 + j) * PADR + lane] = f2bf(v);
            }
        }
#pragma unroll
        for (int ksl = 0; ksl < 2; ++ksl) {
            int ks = c * 2 + ksl;
            short8 bfrag = *(const short8*)&sw[p_ * PADR + ksl * 32 + quad * 8];
#pragma unroll
            for (int ct = 0; ct < 8; ++ct) {
                short8 a = *(const short8*)&wf[(((long)ct * 18 + ks) * 64 + lane) * 8];
                acc[ct] = __builtin_amdgcn_mfma_f32_16x16x32_bf16(a, bfrag, acc[ct], 0, 0, 0);
            }
        }
    }

    long ob = ((long)(b * 128) << 14) + (h << 7) + wpx0 + p_;
#pragma unroll
    for (int ct = 0; ct < 8; ++ct)
#pragma unroll
        for (int r = 0; r < 4; ++r)
            out[ob + ((long)(ct * 16 + quad * 4 + r) << 14)] = acc[ct][r];
}

// BN stats partials
__global__ __launch_bounds__(256) void bn_stats_part_k(const float* __restrict__ y, float* __restrict__ part) {
    int bi = blockIdx.x;
    int c = bi & 127;
    int b = bi >> 7;
    int t = threadIdx.x;
    const float4* p4 = (const float4*)(y + ((long)(b * 128 + c) << 14));
    float sum = 0.f, ss = 0.f;
#pragma unroll
    for (int i = 0; i < 16; ++i) {
        float4 v = p4[t + 256 * i];
        sum += v.x + v.y + v.z + v.w;
        ss  += v.x * v.x + v.y * v.y + v.z * v.z + v.w * v.w;
    }
#pragma unroll
    for (int o = 32; o > 0; o >>= 1) { sum += __shfl_down(sum, o); ss += __shfl_down(ss, o); }
    __shared__ float s1[4], s2[4];
    int wave = t >> 6;
    if ((t & 63) == 0) { s1[wave] = sum; s2[wave] = ss; }
    __syncthreads();
    if (t == 0) {
        part[bi]       = s1[0] + s1[1] + s1[2] + s1[3];
        part[512 + bi] = s2[0] + s2[1] + s2[2] + s2[3];
    }
}

__global__ void bn_final_k(const float* __restrict__ part, const float* __restrict__ g,
                           const float* __restrict__ be, float* __restrict__ ab) {
    int c = threadIdx.x;   // 128 threads
    float sum = 0.f, ss = 0.f;
#pragma unroll
    for (int b = 0; b < 4; ++b) {
        sum += part[b * 128 + c];
        ss  += part[512 + b * 128 + c];
    }
    float mean = sum * (1.f / 65536.f);
    float var  = ss  * (1.f / 65536.f) - mean * mean;
    float inv  = rsqrtf(var + 1e-5f);
    float a = g[c] * inv;
    ab[c]       = a;
    ab[128 + c] = be[c] - mean * a;
}

// BN+ReLU in-place on fp32 NCHW + transposed bf16 NHWC copy
__global__ __launch_bounds__(256) void bn_apply_dual_k(float* __restrict__ y, const float* __restrict__ ab,
                                                       unsigned short* __restrict__ yt) {
    __shared__ __align__(4) short s_t[64 * 134];
    int bi  = blockIdx.x;          // 4 * 256
    int hw0 = (bi & 255) * 64;
    int b   = bi >> 8;
    int t   = threadIdx.x;
    int hwp = t & 63;
#pragma unroll 4
    for (int it = 0; it < 32; ++it) {
        int c = it * 4 + (t >> 6);
        float a = ab[c], sh = ab[128 + c];
        long addr = ((long)(b * 128 + c) << 14) + hw0 + hwp;
        float v = y[addr];
        v = fmaxf(v * a + sh, 0.f);
        y[addr] = v;
        s_t[hwp * 134 + c] = f2bf(v);
    }
    __syncthreads();
#pragma unroll 4
    for (int it = 0; it < 16; ++it) {
        int i   = it * 256 + t;
        int c2  = (i & 63) * 2;
        int hw2 = i >> 6;
        int sv = *(const int*)&s_t[hw2 * 134 + c2];
        *(int*)&yt[((long)((b << 14) + hw0 + hw2)) * 128 + c2] = sv;
    }
}

__global__ __launch_bounds__(256) void bn_apply_out_k(const float* __restrict__ y, const float* __restrict__ ab,
                                                      const int* __restrict__ flag, void* __restrict__ out, int total4) {
    int i = blockIdx.x * 256 + threadIdx.x;
    if (i >= total4) return;
    int c = (i >> 12) & 127;
    float a = ab[c], sh = ab[128 + c];
    float4 v = reinterpret_cast<const float4*>(y)[i];
    v.x = fmaxf(v.x * a + sh, 0.f);
    v.y = fmaxf(v.y * a + sh, 0.f);
    v.z = fmaxf(v.z * a + sh, 0.f);
    v.w = fmaxf(v.w * a + sh, 0.f);
    if (flag[0] != 0) {
        ushort4 u;
        u.x = (unsigned short)f2bf(v.x);
        u.y = (unsigned short)f2bf(v.y);
        u.z = (unsigned short)f2bf(v.z);
        u.w = (unsigned short)f2bf(v.w);
        reinterpret_cast<ushort4*>(out)[i] = u;
    } else {
        reinterpret_cast<float4*>(out)[i] = v;
    }
}

extern "C" void kernel_launch(void* const* d_in, const int* in_sizes, int n_in,
                              void* d_out, int out_size, void* d_ws, size_t ws_size,
                              hipStream_t stream) {
    float* ws   = (float*)d_ws;
    int*   flag = (int*)d_ws;
    float* ab   = ws + WS_AB;
    float* cvt  = ws + WS_CVT;

    const float* X     = cvt + R_X;
    const float* Woff1 = cvt + R_WOFF1;
    const float* Boff1 = cvt + R_BOFF1;
    const float* W1f   = cvt + R_W1;
    const float* B1f   = cvt + R_B1;
    const float* G1    = cvt + R_G1;
    const float* Be1   = cvt + R_BE1;
    const float* Woff2 = cvt + R_WOFF2;
    const float* Boff2 = cvt + R_BOFF2;
    const float* W2f   = cvt + R_W2;
    const float* B2f   = cvt + R_B2;
    const float* G2    = cvt + R_G2;
    const float* Be2   = cvt + R_BE2;

    short* WF1 = (short*)(ws + WS_WF1);
    short* WF2 = (short*)(ws + WS_WF2);
    unsigned short* XT  = (unsigned short*)(ws + WS_XT);
    unsigned short* Y1T = (unsigned short*)(ws + WS_Y1T);
    float* OFF  = ws + WS_OFF;
    float* PART = ws + WS_PART;
    float* Y1   = ws + WS_Y1;
    float* Y2   = ws + WS_Y2;

    SrcPtrs sp;
    for (int j = 0; j < 13; ++j) sp.p[j] = d_in[j];

    probe_dtype_k<<<1, 64, 0, stream>>>((const unsigned int*)d_in[5], flag);
    convert_inputs_k<<<(CVT_TOTAL + 255) / 256, 256, 0, stream>>>(sp, cvt, flag, CVT_TOTAL);
    wf_build_k<64><<<288, 256, 0, stream>>>(W1f, WF1);
    wf_build_k<128><<<576, 256, 0, stream>>>(W2f, WF2);
    xt_build_k<<<1024, 256, 0, stream>>>(X, XT);

    // stage 1
    hipMemsetAsync(OFF, 0, (size_t)KOFF * 65536 * 4, stream);
    conv3x3_atomic_k<64><<<BB * 128 * 4, 256, 0, stream>>>(X, Woff1, Boff1, OFF);
    deform_mfma64_k<<<BB * 128 * 2, 256, 0, stream>>>(XT, OFF, WF1, B1f, Y1);
    bn_stats_part_k<<<512, 256, 0, stream>>>(Y1, PART);
    bn_final_k<<<1, 128, 0, stream>>>(PART, G1, Be1, ab);
    bn_apply_dual_k<<<1024, 256, 0, stream>>>(Y1, ab, Y1T);

    // stage 2
    hipMemsetAsync(OFF, 0, (size_t)KOFF * 65536 * 4, stream);
    conv3x3_atomic_k<128><<<BB * 128 * 4, 256, 0, stream>>>(Y1, Woff2, Boff2, OFF);
    deform_mfma128_k<<<BB * 128 * 2, 256, 0, stream>>>(Y1T, OFF, WF2, B2f, Y2);
    bn_stats_part_k<<<512, 256, 0, stream>>>(Y2, PART);
    bn_final_k<<<1, 128, 0, stream>>>(PART, G2, Be2, ab);
    bn_apply_out_k<<<(BB * 128 * HWP / 4 + 255) / 256, 256, 0, stream>>>(Y2, ab, flag, d_out, BB * 128 * HWP / 4);
}

// Round 12
// 357.060 us; speedup vs baseline: 1.1664x; 1.1664x over previous
//
#include <hip/hip_runtime.h>
#include <hip/hip_bf16.h>

#define BB 4
#define H_ 128
#define W_ 128
#define HWP 16384
#define CIN1 64
#define CMID 128
#define KOFF 18

typedef short short8 __attribute__((ext_vector_type(8)));
typedef float floatx4 __attribute__((ext_vector_type(4)));

// ---- workspace layout (float offsets) ----
#define WS_AB   16
#define WS_CVT  288
#define CVT_TOTAL 4447396
#define WS_WF1  4447744
#define WS_WF2  4484608
#define WS_XT   4558336
#define WS_OFF  6655488          // single offset buffer: 18*65536 floats
#define WS_Y1   7835136
#define WS_Y1T  16223744
#define WS_PART 21600000
#define WS_Y2   WS_Y1            // Y1 (fp32 NCHW) dead after conv2; alias

// cvt-relative input offsets
#define R_X     0
#define R_WOFF1 4194304
#define R_BOFF1 4204672
#define R_W1    4204690
#define R_B1    4278418
#define R_G1    4278546
#define R_BE1   4278674
#define R_WOFF2 4278802
#define R_BOFF2 4299538
#define R_W2    4299556
#define R_B2    4447012
#define R_G2    4447140
#define R_BE2   4447268

struct SrcPtrs { const void* p[13]; };

__device__ inline short f2bf(float f) {
    __hip_bfloat16 h = __float2bfloat16(f);
    return *reinterpret_cast<short*>(&h);
}
__device__ inline float bf2f(unsigned short u) {
    return __uint_as_float(((unsigned int)u) << 16);
}
__device__ inline float bfu_lo(unsigned int u) { return __uint_as_float(u << 16); }
__device__ inline float bfu_hi(unsigned int u) { return __uint_as_float(u & 0xFFFF0000u); }
__device__ inline float rl_f(float v, int i) {
    return __int_as_float(__builtin_amdgcn_readlane(__float_as_int(v), i));
}

__global__ void probe_dtype_k(const unsigned int* __restrict__ g1, int* __restrict__ flag) {
    if (threadIdx.x == 0 && blockIdx.x == 0) {
        flag[0] = ((g1[0] & 0xFFFFu) != 0u) ? 1 : 0;
    }
}

__global__ __launch_bounds__(256) void convert_inputs_k(SrcPtrs sp, float* __restrict__ dst,
                                                        const int* __restrict__ flag, int total) {
    int i = blockIdx.x * 256 + threadIdx.x;
    if (i >= total) return;
    constexpr int prefix[13] = {0, R_WOFF1, R_BOFF1, R_W1, R_B1, R_G1, R_BE1,
                                R_WOFF2, R_BOFF2, R_W2, R_B2, R_G2, R_BE2};
    const void* src = sp.p[0];
    int base = 0;
#pragma unroll
    for (int q = 1; q < 13; ++q) {
        if (i >= prefix[q]) { src = sp.p[q]; base = prefix[q]; }
    }
    int local = i - base;
    float v;
    if (flag[0] != 0) {
        v = bf2f(((const unsigned short*)src)[local]);
    } else {
        v = ((const float*)src)[local];
    }
    dst[i] = v;
}

// Pack conv weights into MFMA A-fragment order; frag-k = kk*CIN + ci
template <int CIN>
__global__ __launch_bounds__(256) void wf_build_k(const float* __restrict__ w, short* __restrict__ wf) {
    constexpr int KSTEPS = CIN * 9 / 32;
    int idx = blockIdx.x * 256 + threadIdx.x;
    int j    = idx & 7;
    int lane = (idx >> 3) & 63;
    int rem  = idx >> 9;
    int ks   = rem % KSTEPS;
    int ct   = rem / KSTEPS;
    int co = ct * 16 + (lane & 15);
    int k  = ks * 32 + (lane >> 4) * 8 + j;
    int ci = k & (CIN - 1);
    int kk = k / CIN;
    wf[idx] = f2bf(w[(co * CIN + ci) * 9 + kk]);
}

// X (fp32 NCHW, C=64) -> XT (bf16 NHWC)
__global__ __launch_bounds__(256) void xt_build_k(const float* __restrict__ x, unsigned short* __restrict__ xt) {
    __shared__ __align__(4) short s_t[64 * 66];
    int bi  = blockIdx.x;           // 4 * 256
    int hw0 = (bi & 255) * 64;
    int b   = bi >> 8;
    int t   = threadIdx.x;
    int hwp = t & 63;
#pragma unroll
    for (int it = 0; it < 16; ++it) {
        int c = it * 4 + (t >> 6);
        float v = x[((long)(b * 64 + c) << 14) + hw0 + hwp];
        s_t[hwp * 66 + c] = f2bf(v);
    }
    __syncthreads();
#pragma unroll
    for (int it = 0; it < 8; ++it) {
        int i  = it * 256 + t;
        int c2 = (i & 31) * 2;
        int hw2 = i >> 5;
        int sv = *(const int*)&s_t[hw2 * 66 + c2];
        *(int*)&xt[((long)((b << 14) + hw0 + hw2)) * 64 + c2] = sv;
    }
}

// Offset conv3x3, pad=1, CO=18, ci-QUARTER split, atomicAdd accumulation.
template <int CIN>
__global__ __launch_bounds__(256) void conv3x3_atomic_k(const float* __restrict__ x,
                                                        const float* __restrict__ w,
                                                        const float* __restrict__ bias,
                                                        float* __restrict__ outp) {
    constexpr int CIQ = CIN / 4;
    int bi = blockIdx.x;
    int h  = bi & 127;
    int b  = (bi >> 7) & 3;
    int q  = bi >> 9;
    int t  = threadIdx.x;
    int wq = t & 127;
    int cg = __builtin_amdgcn_readfirstlane(t >> 7);
    int co0 = cg * 9;
    int ci0 = q * CIQ;

    float acc[9];
#pragma unroll
    for (int j = 0; j < 9; ++j) acc[j] = (q == 0) ? bias[co0 + j] : 0.f;

    const float* xb = x + ((long)(b * CIN + ci0) << 14);
    bool bm = h > 0, bp = h < H_ - 1, bl = wq > 0, br = wq < W_ - 1;
    int rm = (bm ? h - 1 : 0) << 7;
    int rc = h << 7;
    int rp = (bp ? h + 1 : H_ - 1) << 7;

#pragma unroll 2
    for (int ci = 0; ci < CIQ; ++ci) {
        const float* plane = xb + ((long)ci << 14);
        float v0 = plane[rm + wq - 1], v1 = plane[rm + wq], v2 = plane[rm + wq + 1];
        float v3 = plane[rc + wq - 1], v4 = plane[rc + wq], v5 = plane[rc + wq + 1];
        float v6 = plane[rp + wq - 1], v7 = plane[rp + wq], v8 = plane[rp + wq + 1];
        v0 = (bm && bl) ? v0 : 0.f;
        v1 = bm ? v1 : 0.f;
        v2 = (bm && br) ? v2 : 0.f;
        v3 = bl ? v3 : 0.f;
        v5 = br ? v5 : 0.f;
        v6 = (bp && bl) ? v6 : 0.f;
        v7 = bp ? v7 : 0.f;
        v8 = (bp && br) ? v8 : 0.f;
#pragma unroll
        for (int j = 0; j < 9; ++j) {
            const float* wk = w + ((long)(co0 + j) * CIN + ci0 + ci) * 9;
            acc[j] += v0 * wk[0] + v1 * wk[1] + v2 * wk[2]
                    + v3 * wk[3] + v4 * wk[4] + v5 * wk[5]
                    + v6 * wk[6] + v7 * wk[7] + v8 * wk[8];
        }
    }

    long ob = ((long)(b * KOFF + co0) << 14) + (h << 7) + wq;
#pragma unroll
    for (int j = 0; j < 9; ++j) atomicAdd(&outp[ob + ((long)j << 14)], acc[j]);
}

// ---- deform table build (per wave, lane i owns row r = wv + 4*i, i < 36) ----
template <int CIN>
__device__ inline void build_table(const float* __restrict__ off, int b, int h, int w0,
                                   int lane, int wv,
                                   int& tpk, float& tw0, float& tw1, float& tw2, float& tw3) {
    tpk = 0; tw0 = tw1 = tw2 = tw3 = 0.f;
    if (lane < 36) {
        int r = wv + 4 * lane;
        int p = r & 15;
        int k = r >> 4;
        int wpix = w0 + p;
        long obase = ((long)(b * KOFF) << 14) + (h << 7) + wpix;
        float oy = off[obase + ((long)(2 * k) << 14)];
        float ox = off[obase + ((long)(2 * k + 1) << 14)];
        float py = (float)(h - 1 + (k / 3)) + oy;
        float px = (float)(wpix - 1 + (k % 3)) + ox;
        float fy = floorf(py), fx = floorf(px);
        float wy = py - fy, wx = px - fx;
        int y0 = (int)fy, x0 = (int)fx;
        int y1 = y0 + 1, x1 = x0 + 1;
        bool vy0 = (y0 >= 0) && (y0 < H_);
        bool vy1 = (y1 >= 0) && (y1 < H_);
        bool vx0 = (x0 >= 0) && (x0 < W_);
        bool vx1 = (x1 >= 0) && (x1 < W_);
        float wy0 = 1.f - wy, wx0 = 1.f - wx;
        tw0 = (vy0 && vx0) ? wy0 * wx0 : 0.f;
        tw1 = (vy0 && vx1) ? wy0 * wx  : 0.f;
        tw2 = (vy1 && vx0) ? wy  * wx0 : 0.f;
        tw3 = (vy1 && vx1) ? wy  * wx  : 0.f;
        int iy0 = min(max(y0, 0), H_ - 1), iy1 = min(max(y1, 0), H_ - 1);
        int ix0 = min(max(x0, 0), W_ - 1), ix1 = min(max(x1, 0), W_ - 1);
        int dx = ix1 - ix0;
        int dy = iy1 - iy0;
        tpk = (iy0 * W_ + ix0) | (dx << 14) | (dy << 15);
    }
}

// Batched gather, CIN=128
template <int NB>
__device__ inline void gather_batch128(const unsigned short* __restrict__ xb, short* __restrict__ s_samp,
                                       int PADc, int i0, int kkbase, int wv, int lane,
                                       int tpk, float tw0, float tw1, float tw2, float tw3) {
    uint4 ub[NB];
#pragma unroll
    for (int j = 0; j < NB; ++j) {
        int pk = __builtin_amdgcn_readlane(tpk, i0 + j);
        const unsigned short* b00 = xb + (pk & 0x3FFF) * 128;
        const unsigned short* b01 = b00 + ((pk >> 14) & 1) * 128;
        const unsigned short* b10 = b00 + ((pk >> 15) & 1) * (W_ * 128);
        const unsigned short* b11 = b01 + ((pk >> 15) & 1) * (W_ * 128);
        ub[j].x = *(const unsigned int*)(b00 + 2 * lane);
        ub[j].y = *(const unsigned int*)(b01 + 2 * lane);
        ub[j].z = *(const unsigned int*)(b10 + 2 * lane);
        ub[j].w = *(const unsigned int*)(b11 + 2 * lane);
    }
#pragma unroll
    for (int j = 0; j < NB; ++j) {
        int i = i0 + j;
        int r = wv + 4 * i;
        float w00 = rl_f(tw0, i), w01 = rl_f(tw1, i), w10 = rl_f(tw2, i), w11 = rl_f(tw3, i);
        float vlo = w00 * bfu_lo(ub[j].x) + w01 * bfu_lo(ub[j].y)
                  + w10 * bfu_lo(ub[j].z) + w11 * bfu_lo(ub[j].w);
        float vhi = w00 * bfu_hi(ub[j].x) + w01 * bfu_hi(ub[j].y)
                  + w10 * bfu_hi(ub[j].z) + w11 * bfu_hi(ub[j].w);
        __hip_bfloat162 h2 = __float22bfloat162_rn(make_float2(vlo, vhi));
        *(unsigned int*)&s_samp[(r & 15) * PADc + ((r >> 4) - kkbase) * 128 + 2 * lane] =
            *reinterpret_cast<unsigned int*>(&h2);
    }
}

// Batched gather, CIN=64
template <int NB>
__device__ inline void gather_batch64(const unsigned short* __restrict__ xb, short* __restrict__ s_samp,
                                      int PADc, int i0, int wv, int lane,
                                      int tpk, float tw0, float tw1, float tw2, float tw3) {
    unsigned short q0[NB], q1[NB], q2[NB], q3[NB];
#pragma unroll
    for (int j = 0; j < NB; ++j) {
        int pk = __builtin_amdgcn_readlane(tpk, i0 + j);
        const unsigned short* b00 = xb + (pk & 0x3FFF) * 64;
        const unsigned short* b01 = b00 + ((pk >> 14) & 1) * 64;
        const unsigned short* b10 = b00 + ((pk >> 15) & 1) * (W_ * 64);
        const unsigned short* b11 = b01 + ((pk >> 15) & 1) * (W_ * 64);
        q0[j] = b00[lane]; q1[j] = b01[lane]; q2[j] = b10[lane]; q3[j] = b11[lane];
    }
#pragma unroll
    for (int j = 0; j < NB; ++j) {
        int i = i0 + j;
        int r = wv + 4 * i;
        float w00 = rl_f(tw0, i), w01 = rl_f(tw1, i), w10 = rl_f(tw2, i), w11 = rl_f(tw3, i);
        float v = w00 * bf2f(q0[j]) + w01 * bf2f(q1[j]) + w10 * bf2f(q2[j]) + w11 * bf2f(q3[j]);
        s_samp[(r & 15) * PADc + (r >> 4) * 64 + lane] = f2bf(v);
    }
}

// Deform conv via MFMA, CIN=64.  LDS 18.7 KB; 6 blocks/CU
__global__ __launch_bounds__(256, 6) void deform_mfma64_k(const unsigned short* __restrict__ xt,
                                                          const float* __restrict__ off,
                                                          const short* __restrict__ wf,
                                                          const float* __restrict__ bias,
                                                          float* __restrict__ out) {
    constexpr int CIN = 64;
    constexpr int K = 576;
    constexpr int PADc = K + 8;
    constexpr int KSTEPS = K / 32;
    __shared__ __align__(16) short s_samp[16 * PADc];

    int bi = blockIdx.x;
    int w0 = (bi & 7) * 16;
    int h  = (bi >> 3) & 127;
    int b  = bi >> 10;
    int t  = threadIdx.x;
    int lane = t & 63;
    int wv   = t >> 6;

    int tpk; float tw0, tw1, tw2, tw3;
    build_table<CIN>(off, b, h, w0, lane, wv, tpk, tw0, tw1, tw2, tw3);
    const unsigned short* xb = xt + (long)b * HWP * CIN;

    gather_batch64<12>(xb, s_samp, PADc,  0, wv, lane, tpk, tw0, tw1, tw2, tw3);
    gather_batch64<12>(xb, s_samp, PADc, 12, wv, lane, tpk, tw0, tw1, tw2, tw3);
    gather_batch64<12>(xb, s_samp, PADc, 24, wv, lane, tpk, tw0, tw1, tw2, tw3);
    __syncthreads();

    int p_   = lane & 15;
    int quad = lane >> 4;
    int ct0 = wv * 2, ct1 = wv * 2 + 1;
    floatx4 acc0, acc1;
#pragma unroll
    for (int r = 0; r < 4; ++r) {
        acc0[r] = bias[ct0 * 16 + quad * 4 + r];
        acc1[r] = bias[ct1 * 16 + quad * 4 + r];
    }
#pragma unroll 3
    for (int ks = 0; ks < KSTEPS; ++ks) {
        short8 bfrag = *(const short8*)&s_samp[p_ * PADc + ks * 32 + quad * 8];
        short8 a0 = *(const short8*)&wf[(((long)ct0 * KSTEPS + ks) * 64 + lane) * 8];
        short8 a1 = *(const short8*)&wf[(((long)ct1 * KSTEPS + ks) * 64 + lane) * 8];
        acc0 = __builtin_amdgcn_mfma_f32_16x16x32_bf16(a0, bfrag, acc0, 0, 0, 0);
        acc1 = __builtin_amdgcn_mfma_f32_16x16x32_bf16(a1, bfrag, acc1, 0, 0, 0);
    }

    long ob = ((long)(b * 128) << 14) + (h << 7) + w0 + p_;
#pragma unroll
    for (int r = 0; r < 4; ++r) {
        out[ob + ((long)(ct0 * 16 + quad * 4 + r) << 14)] = acc0[r];
        out[ob + ((long)(ct1 * 16 + quad * 4 + r) << 14)] = acc1[r];
    }
}

// Deform conv via MFMA, CIN=128: kk-chunked.  LDS 20.7 KB; 6 blocks/CU
__global__ __launch_bounds__(256, 6) void deform_mfma128_k(const unsigned short* __restrict__ xt,
                                                           const float* __restrict__ off,
                                                           const short* __restrict__ wf,
                                                           const float* __restrict__ bias,
                                                           float* __restrict__ out) {
    constexpr int KSTEPS = 36;
    constexpr int PADc = 5 * 128 + 8;
    __shared__ __align__(16) short s_samp[16 * PADc];

    int bi = blockIdx.x;
    int w0 = (bi & 7) * 16;
    int h  = (bi >> 3) & 127;
    int b  = bi >> 10;
    int t  = threadIdx.x;
    int lane = t & 63;
    int wv   = t >> 6;

    int tpk; float tw0, tw1, tw2, tw3;
    build_table<128>(off, b, h, w0, lane, wv, tpk, tw0, tw1, tw2, tw3);
    const unsigned short* xb = xt + (long)b * HWP * 128;

    int p_   = lane & 15;
    int quad = lane >> 4;
    int ct0 = wv * 2, ct1 = wv * 2 + 1;
    floatx4 acc0, acc1;
#pragma unroll
    for (int r = 0; r < 4; ++r) {
        acc0[r] = bias[ct0 * 16 + quad * 4 + r];
        acc1[r] = bias[ct1 * 16 + quad * 4 + r];
    }

    gather_batch128<8>(xb, s_samp, PADc, 0, 0, wv, lane, tpk, tw0, tw1, tw2, tw3);
    gather_batch128<8>(xb, s_samp, PADc, 8, 0, wv, lane, tpk, tw0, tw1, tw2, tw3);
    __syncthreads();
#pragma unroll 4
    for (int ks = 0; ks < 16; ++ks) {
        short8 bfrag = *(const short8*)&s_samp[p_ * PADc + ks * 32 + quad * 8];
        short8 a0 = *(const short8*)&wf[(((long)ct0 * KSTEPS + ks) * 64 + lane) * 8];
        short8 a1 = *(const short8*)&wf[(((long)ct1 * KSTEPS + ks) * 64 + lane) * 8];
        acc0 = __builtin_amdgcn_mfma_f32_16x16x32_bf16(a0, bfrag, acc0, 0, 0, 0);
        acc1 = __builtin_amdgcn_mfma_f32_16x16x32_bf16(a1, bfrag, acc1, 0, 0, 0);
    }
    __syncthreads();

    gather_batch128<10>(xb, s_samp, PADc, 16, 4, wv, lane, tpk, tw0, tw1, tw2, tw3);
    gather_batch128<10>(xb, s_samp, PADc, 26, 4, wv, lane, tpk, tw0, tw1, tw2, tw3);
    __syncthreads();
#pragma unroll 4
    for (int ks = 16; ks < 36; ++ks) {
        short8 bfrag = *(const short8*)&s_samp[p_ * PADc + (ks - 16) * 32 + quad * 8];
        short8 a0 = *(const short8*)&wf[(((long)ct0 * KSTEPS + ks) * 64 + lane) * 8];
        short8 a1 = *(const short8*)&wf[(((long)ct1 * KSTEPS + ks) * 64 + lane) * 8];
        acc0 = __builtin_amdgcn_mfma_f32_16x16x32_bf16(a0, bfrag, acc0, 0, 0, 0);
        acc1 = __builtin_amdgcn_mfma_f32_16x16x32_bf16(a1, bfrag, acc1, 0, 0, 0);
    }

    long ob = ((long)(b * 128) << 14) + (h << 7) + w0 + p_;
#pragma unroll
    for (int r = 0; r < 4; ++r) {
        out[ob + ((long)(ct0 * 16 + quad * 4 + r) << 14)] = acc0[r];
        out[ob + ((long)(ct1 * 16 + quad * 4 + r) << 14)] = acc1[r];
    }
}

// BN stats partials: 512 blocks, one (c,b) plane each
__global__ __launch_bounds__(256) void bn_stats_part_k(const float* __restrict__ y, float* __restrict__ part) {
    int bi = blockIdx.x;
    int c = bi & 127;
    int b = bi >> 7;
    int t = threadIdx.x;
    const float4* p4 = (const float4*)(y + ((long)(b * 128 + c) << 14));
    float sum = 0.f, ss = 0.f;
#pragma unroll
    for (int i = 0; i < 16; ++i) {
        float4 v = p4[t + 256 * i];
        sum += v.x + v.y + v.z + v.w;
        ss  += v.x * v.x + v.y * v.y + v.z * v.z + v.w * v.w;
    }
#pragma unroll
    for (int o = 32; o > 0; o >>= 1) { sum += __shfl_down(sum, o); ss += __shfl_down(ss, o); }
    __shared__ float s1[4], s2[4];
    int wave = t >> 6;
    if ((t & 63) == 0) { s1[wave] = sum; s2[wave] = ss; }
    __syncthreads();
    if (t == 0) {
        part[bi]       = s1[0] + s1[1] + s1[2] + s1[3];
        part[512 + bi] = s2[0] + s2[1] + s2[2] + s2[3];
    }
}

// BN+ReLU in-place on fp32 NCHW + transposed bf16 NHWC copy.
// Scale/shift computed per-block from PART (bn_final folded in).
__global__ __launch_bounds__(256) void bn_apply_dual_k(float* __restrict__ y, const float* __restrict__ part,
                                                       const float* __restrict__ g, const float* __restrict__ be,
                                                       unsigned short* __restrict__ yt) {
    __shared__ __align__(4) short s_t[64 * 134];
    __shared__ float s_a[128], s_sh[128];
    int t = threadIdx.x;
    if (t < 128) {
        float sum = part[t] + part[128 + t] + part[256 + t] + part[384 + t];
        float ss  = part[512 + t] + part[640 + t] + part[768 + t] + part[896 + t];
        float mean = sum * (1.f / 65536.f);
        float var  = ss  * (1.f / 65536.f) - mean * mean;
        float inv  = rsqrtf(var + 1e-5f);
        float a = g[t] * inv;
        s_a[t]  = a;
        s_sh[t] = be[t] - mean * a;
    }
    __syncthreads();

    int bi  = blockIdx.x;          // 4 * 256
    int hw0 = (bi & 255) * 64;
    int b   = bi >> 8;
    int hwp = t & 63;
#pragma unroll 4
    for (int it = 0; it < 32; ++it) {
        int c = it * 4 + (t >> 6);
        float a = s_a[c], sh = s_sh[c];
        long addr = ((long)(b * 128 + c) << 14) + hw0 + hwp;
        float v = y[addr];
        v = fmaxf(v * a + sh, 0.f);
        y[addr] = v;
        s_t[hwp * 134 + c] = f2bf(v);
    }
    __syncthreads();
#pragma unroll 4
    for (int it = 0; it < 16; ++it) {
        int i   = it * 256 + t;
        int c2  = (i & 63) * 2;
        int hw2 = i >> 6;
        int sv = *(const int*)&s_t[hw2 * 134 + c2];
        *(int*)&yt[((long)((b << 14) + hw0 + hw2)) * 128 + c2] = sv;
    }
}

// Final BN+ReLU -> d_out (fp32 or bf16 per flag). bn_final folded in.
__global__ __launch_bounds__(256) void bn_apply_out_k(const float* __restrict__ y, const float* __restrict__ part,
                                                      const float* __restrict__ g, const float* __restrict__ be,
                                                      const int* __restrict__ flag, void* __restrict__ out, int total4) {
    __shared__ float s_a[128], s_sh[128];
    int t = threadIdx.x;
    if (t < 128) {
        float sum = part[t] + part[128 + t] + part[256 + t] + part[384 + t];
        float ss  = part[512 + t] + part[640 + t] + part[768 + t] + part[896 + t];
        float mean = sum * (1.f / 65536.f);
        float var  = ss  * (1.f / 65536.f) - mean * mean;
        float inv  = rsqrtf(var + 1e-5f);
        float a = g[t] * inv;
        s_a[t]  = a;
        s_sh[t] = be[t] - mean * a;
    }
    __syncthreads();

    int i = blockIdx.x * 256 + t;
    if (i >= total4) return;
    int c = (i >> 12) & 127;
    float a = s_a[c], sh = s_sh[c];
    float4 v = reinterpret_cast<const float4*>(y)[i];
    v.x = fmaxf(v.x * a + sh, 0.f);
    v.y = fmaxf(v.y * a + sh, 0.f);
    v.z = fmaxf(v.z * a + sh, 0.f);
    v.w = fmaxf(v.w * a + sh, 0.f);
    if (flag[0] != 0) {
        ushort4 u;
        u.x = (unsigned short)f2bf(v.x);
        u.y = (unsigned short)f2bf(v.y);
        u.z = (unsigned short)f2bf(v.z);
        u.w = (unsigned short)f2bf(v.w);
        reinterpret_cast<ushort4*>(out)[i] = u;
    } else {
        reinterpret_cast<float4*>(out)[i] = v;
    }
}

extern "C" void kernel_launch(void* const* d_in, const int* in_sizes, int n_in,
                              void* d_out, int out_size, void* d_ws, size_t ws_size,
                              hipStream_t stream) {
    float* ws   = (float*)d_ws;
    int*   flag = (int*)d_ws;
    float* cvt  = ws + WS_CVT;

    const float* X     = cvt + R_X;
    const float* Woff1 = cvt + R_WOFF1;
    const float* Boff1 = cvt + R_BOFF1;
    const float* W1f   = cvt + R_W1;
    const float* B1f   = cvt + R_B1;
    const float* G1    = cvt + R_G1;
    const float* Be1   = cvt + R_BE1;
    const float* Woff2 = cvt + R_WOFF2;
    const float* Boff2 = cvt + R_BOFF2;
    const float* W2f   = cvt + R_W2;
    const float* B2f   = cvt + R_B2;
    const float* G2    = cvt + R_G2;
    const float* Be2   = cvt + R_BE2;

    short* WF1 = (short*)(ws + WS_WF1);
    short* WF2 = (short*)(ws + WS_WF2);
    unsigned short* XT  = (unsigned short*)(ws + WS_XT);
    unsigned short* Y1T = (unsigned short*)(ws + WS_Y1T);
    float* OFF  = ws + WS_OFF;
    float* PART = ws + WS_PART;
    float* Y1   = ws + WS_Y1;
    float* Y2   = ws + WS_Y2;

    SrcPtrs sp;
    for (int j = 0; j < 13; ++j) sp.p[j] = d_in[j];

    probe_dtype_k<<<1, 64, 0, stream>>>((const unsigned int*)d_in[5], flag);
    convert_inputs_k<<<(CVT_TOTAL + 255) / 256, 256, 0, stream>>>(sp, cvt, flag, CVT_TOTAL);
    wf_build_k<64><<<288, 256, 0, stream>>>(W1f, WF1);
    wf_build_k<128><<<576, 256, 0, stream>>>(W2f, WF2);
    xt_build_k<<<1024, 256, 0, stream>>>(X, XT);

    // stage 1
    hipMemsetAsync(OFF, 0, (size_t)KOFF * 65536 * 4, stream);
    conv3x3_atomic_k<64><<<BB * 128 * 4, 256, 0, stream>>>(X, Woff1, Boff1, OFF);
    deform_mfma64_k<<<BB * 128 * 8, 256, 0, stream>>>(XT, OFF, WF1, B1f, Y1);
    bn_stats_part_k<<<512, 256, 0, stream>>>(Y1, PART);
    bn_apply_dual_k<<<1024, 256, 0, stream>>>(Y1, PART, G1, Be1, Y1T);

    // stage 2
    hipMemsetAsync(OFF, 0, (size_t)KOFF * 65536 * 4, stream);
    conv3x3_atomic_k<128><<<BB * 128 * 4, 256, 0, stream>>>(Y1, Woff2, Boff2, OFF);
    deform_mfma128_k<<<BB * 128 * 8, 256, 0, stream>>>(Y1T, OFF, WF2, B2f, Y2);
    bn_stats_part_k<<<512, 256, 0, stream>>>(Y2, PART);
    bn_apply_out_k<<<(BB * 128 * HWP / 4 + 255) / 256, 256, 0, stream>>>(Y2, PART, G2, Be2, flag, d_out, BB * 128 * HWP / 4);
}